// Round 2
// baseline (753.187 us; speedup 1.0000x reference)
//
#include <hip/hip_runtime.h>

// Problem constants (from reference): N_ATOMS=2e6, D_FEAT=64, OUT_DIM=1,
// N_SPECIES=8, N_STRUCTURES=20000, structural_indices SORTED ascending.

#define DF      64
#define NSPEC   8
#define BLOCK   256
#define CHUNK   2048     // atoms per block
#define NBINS   1024     // LDS segment bins per block (chunk spans ~20 structs typ.)

__global__ void zero_out_kernel(float* __restrict__ out, int n) {
    int i = blockIdx.x * blockDim.x + threadIdx.x;
    if (i < n) out[i] = 0.0f;
}

__global__ __launch_bounds__(BLOCK, 4)
void atoms_segsum_kernel(const float* __restrict__ X,
                         const float* __restrict__ W,        // [NSPEC][DF]
                         const int*   __restrict__ species,  // [N]
                         const int*   __restrict__ sidx,     // [N] sorted
                         float*       __restrict__ out,      // [n_structures]
                         int n_atoms)
{
    // W transposed to [feature][species]: lane reads w_lds[f*8+s] -> all 16
    // lanes of a group hit the SAME address (same f per lane within its quad,
    // same s) -> LDS broadcast, zero bank conflicts.
    __shared__ float w_lds[DF * NSPEC];   // 2 KB
    __shared__ float bins[NBINS];         // 4 KB

    const int t = threadIdx.x;

    for (int i = t; i < DF * NSPEC; i += BLOCK) {
        const int s = i & 7;        // species
        const int f = i >> 3;       // feature
        w_lds[i] = W[s * DF + f];   // transpose on stage
    }
    for (int i = t; i < NBINS; i += BLOCK) bins[i] = 0.0f;

    const long long a0 = (long long)blockIdx.x * CHUNK;
    const int s_first = sidx[a0];   // sorted => all s in chunk >= s_first

    __syncthreads();

    const int group  = t >> 4;          // 0..15 : which atom of the 16/iter
    const int lane16 = t & 15;          // 0..15 : which feature quad
    const int fl     = lane16 << 2;     // feature offset 0,4,...,60

    // Leader-lane run accumulation (sidx sorted => runs along the stride-16
    // atom sequence). Cuts LDS atomics ~6x.
    int   run_rel = -1;
    float run_acc = 0.0f;

    for (int it = 0; it < CHUNK; it += 16) {
        const long long a = a0 + it + group;
        if (a < n_atoms) {
            const int s = species[a];
            // Coalesced: wave reads contiguous 1 KB (4 atoms x 256 B).
            const float4 x = *(const float4*)(X + a * DF + fl);
            const float* wp = w_lds + fl * NSPEC + s;   // broadcast reads
            float v = x.x * wp[0] + x.y * wp[8] + x.z * wp[16] + x.w * wp[24];
            // Reduce across the 16 lanes sharing this atom (16-aligned groups,
            // xor masks 1..8 stay inside the group on wave64).
            v += __shfl_xor(v, 1);
            v += __shfl_xor(v, 2);
            v += __shfl_xor(v, 4);
            v += __shfl_xor(v, 8);
            if (lane16 == 0) {
                const int rel = sidx[a] - s_first;
                if (rel == run_rel) {
                    run_acc += v;
                } else {
                    if (run_rel >= 0) {
                        if (run_rel < NBINS) atomicAdd(&bins[run_rel], run_acc);
                        else                 atomicAdd(&out[s_first + run_rel], run_acc);
                    }
                    run_rel = rel;
                    run_acc = v;
                }
            }
        }
    }
    // Flush the last run.
    if (lane16 == 0 && run_rel >= 0) {
        if (run_rel < NBINS) atomicAdd(&bins[run_rel], run_acc);
        else                 atomicAdd(&out[s_first + run_rel], run_acc);
    }

    __syncthreads();

    // Flush non-zero bins: ~chunk/100 global atomics per block.
    for (int i = t; i < NBINS; i += BLOCK) {
        const float v = bins[i];
        if (v != 0.0f) atomicAdd(&out[s_first + i], v);
    }
}

extern "C" void kernel_launch(void* const* d_in, const int* in_sizes, int n_in,
                              void* d_out, int out_size, void* d_ws, size_t ws_size,
                              hipStream_t stream) {
    const float* X       = (const float*)d_in[0];   // [N, 64]
    const float* W       = (const float*)d_in[1];   // [8, 64, 1]
    const int*   species = (const int*)d_in[2];     // [N]
    const int*   sidx    = (const int*)d_in[3];     // [N] sorted
    float*       out     = (float*)d_out;           // [n_structures]

    const int n_atoms = in_sizes[0] / DF;

    // d_out is poisoned before every timed replay -> zero it first.
    {
        int blocks = (out_size + BLOCK - 1) / BLOCK;
        zero_out_kernel<<<blocks, BLOCK, 0, stream>>>(out, out_size);
    }

    const int nblocks = (int)((n_atoms + CHUNK - 1) / CHUNK);
    atoms_segsum_kernel<<<nblocks, BLOCK, 0, stream>>>(X, W, species, sidx,
                                                       out, n_atoms);
}

// Round 3
// 699.839 us; speedup vs baseline: 1.0762x; 1.0762x over previous
//
#include <hip/hip_runtime.h>

// Problem constants (from reference): N_ATOMS=2e6, D_FEAT=64, OUT_DIM=1,
// N_SPECIES=8, N_STRUCTURES=20000, structural_indices SORTED ascending.

#define DF      64
#define NSPEC   8
#define BLOCK   256
#define CHUNK   2048     // atoms per block
#define NBINS   1024     // LDS segment bins (chunk spans ~20 structs typ.)
#define UNROLL  8        // independent loads in flight per thread

__global__ void zero_out_kernel(float* __restrict__ out, int n) {
    int i = blockIdx.x * blockDim.x + threadIdx.x;
    if (i < n) out[i] = 0.0f;
}

__global__ __launch_bounds__(BLOCK, 4)
void atoms_segsum_kernel(const float* __restrict__ X,
                         const float* __restrict__ W,        // [NSPEC][DF]
                         const int*   __restrict__ species,  // [N]
                         const int*   __restrict__ sidx,     // [N] sorted
                         float*       __restrict__ out,      // [n_structures]
                         int n_atoms)
{
    // W transposed to [feature][species]: all 16 lanes of a group read the
    // SAME address -> LDS broadcast, zero bank conflicts.
    __shared__ float w_lds[DF * NSPEC];   // 2 KB
    __shared__ float bins[NBINS];         // 4 KB

    const int t = threadIdx.x;

    for (int i = t; i < DF * NSPEC; i += BLOCK) {
        const int s = i & 7;        // species
        const int f = i >> 3;       // feature
        w_lds[i] = W[s * DF + f];   // transpose on stage
    }
    for (int i = t; i < NBINS; i += BLOCK) bins[i] = 0.0f;

    const long long a0 = (long long)blockIdx.x * CHUNK;
    const int s_first = sidx[a0];   // sorted => all s in chunk >= s_first

    __syncthreads();

    const int group  = t >> 4;          // 0..15 : which atom of the 16/iter
    const int lane16 = t & 15;          // 0..15 : which feature quad
    const int fl     = lane16 << 2;     // feature offset 0,4,...,60
    const float* wbase = w_lds + fl * NSPEC;

    if (a0 + CHUNK <= n_atoms) {
        // HOT PATH: full chunk, no bounds checks. Batch UNROLL independent
        // 1KB-per-wave loads before any use -> 8 KB in flight per wave,
        // latency fully hidden.
        for (int it = 0; it < CHUNK; it += 16 * UNROLL) {
            float4 x[UNROLL];
            int    sp[UNROLL], si[UNROLL];
            #pragma unroll
            for (int u = 0; u < UNROLL; u++) {
                const long long a = a0 + it + u * 16 + group;
                x[u]  = *(const float4*)(X + a * DF + fl);  // wave: contig 1KB
                sp[u] = species[a];
                si[u] = sidx[a];
            }
            #pragma unroll
            for (int u = 0; u < UNROLL; u++) {
                const float* wp = wbase + sp[u];
                float v = x[u].x * wp[0]  + x[u].y * wp[8]
                        + x[u].z * wp[16] + x[u].w * wp[24];
                v += __shfl_xor(v, 1);
                v += __shfl_xor(v, 2);
                v += __shfl_xor(v, 4);
                v += __shfl_xor(v, 8);
                if (lane16 == 0) {
                    const int rel = si[u] - s_first;
                    if (rel < NBINS) atomicAdd(&bins[rel], v);
                    else             atomicAdd(&out[si[u]], v);
                }
            }
        }
    } else {
        // TAIL (one block): per-atom guard.
        for (int it = 0; it < CHUNK; it += 16) {
            const long long a = a0 + it + group;
            if (a < n_atoms) {
                const int s = species[a];
                const float4 x = *(const float4*)(X + a * DF + fl);
                const float* wp = wbase + s;
                float v = x.x * wp[0] + x.y * wp[8] + x.z * wp[16] + x.w * wp[24];
                v += __shfl_xor(v, 1);
                v += __shfl_xor(v, 2);
                v += __shfl_xor(v, 4);
                v += __shfl_xor(v, 8);
                if (lane16 == 0) {
                    const int si  = sidx[a];
                    const int rel = si - s_first;
                    if (rel < NBINS) atomicAdd(&bins[rel], v);
                    else             atomicAdd(&out[si], v);
                }
            }
        }
    }

    __syncthreads();

    // Flush non-zero bins: ~20 global atomics per block.
    for (int i = t; i < NBINS; i += BLOCK) {
        const float v = bins[i];
        if (v != 0.0f) atomicAdd(&out[s_first + i], v);
    }
}

extern "C" void kernel_launch(void* const* d_in, const int* in_sizes, int n_in,
                              void* d_out, int out_size, void* d_ws, size_t ws_size,
                              hipStream_t stream) {
    const float* X       = (const float*)d_in[0];   // [N, 64]
    const float* W       = (const float*)d_in[1];   // [8, 64, 1]
    const int*   species = (const int*)d_in[2];     // [N]
    const int*   sidx    = (const int*)d_in[3];     // [N] sorted
    float*       out     = (float*)d_out;           // [n_structures]

    const int n_atoms = in_sizes[0] / DF;

    // d_out is poisoned before every timed replay -> zero it first.
    {
        int blocks = (out_size + BLOCK - 1) / BLOCK;
        zero_out_kernel<<<blocks, BLOCK, 0, stream>>>(out, out_size);
    }

    const int nblocks = (int)((n_atoms + CHUNK - 1) / CHUNK);
    atoms_segsum_kernel<<<nblocks, BLOCK, 0, stream>>>(X, W, species, sidx,
                                                       out, n_atoms);
}